// Round 13
// baseline (1032.227 us; speedup 1.0000x reference)
//
#include <hip/hip_runtime.h>

typedef unsigned short u16;
typedef __attribute__((ext_vector_type(4))) float v4f;
typedef __attribute__((ext_vector_type(8))) short v8bf;

extern "C" __device__ float __ocml_native_exp2_f32(float);  // bare v_exp_f32
__device__ inline float ex2(float x){ return __ocml_native_exp2_f32(x); }

__device__ inline u16 f2bf(float f){
  union { float f; unsigned u; } v; v.f = f;
  unsigned r = (v.u + 0x7FFFu + ((v.u >> 16) & 1u)) >> 16;
  return (u16)r;
}
__device__ inline float bf2f(u16 u){
  union { unsigned u; float f; } v; v.u = ((unsigned)u) << 16;
  return v.f;
}

#define GLD_LDS16(gp, lp) \
  __builtin_amdgcn_global_load_lds((const __attribute__((address_space(1))) void*)(gp), \
                                   (__attribute__((address_space(3))) void*)(lp), 16, 0, 0)
#define VMCNT(n) asm volatile("s_waitcnt vmcnt(" #n ")" ::: "memory")
#define LGKM0 do { asm volatile("s_waitcnt lgkmcnt(0)" ::: "memory"); \
                   __builtin_amdgcn_sched_barrier(0); } while (0)

// ---------------------------------------------------------------------------
// gemm10b: read-ahead 8-phase schedule, race-fixed vs R12.
// 256x256 tile, BK=64, 8 waves (2Mx4N), LDS 2 x {A0,A1,B0,B1} x 8192 u16.
// Iteration = 2 K-steps (even->buf0, odd->buf1), quadrants (0,0)(0,1)(1,0)(1,1).
// Fixes: stageA(.,0) moved AFTER the frag8-15 A-read (p1/p5, WAR); prologue
// VMCNT(0); uniform VMCNT(6) at p2/p3/p6/p7 (full ledger sim: every stage
// retired before its dependent read, iter0 + steady + tail); final iteration
// PEELED with VMCNT(0) at its p2 (queue stops advancing at tail).
// FUSE: 0 = bf16+bias, 1 = bf16+bias+ReLU, 2 = bf16 split-K partial (no bias)
// ---------------------------------------------------------------------------
template<int FUSE>
__global__ __launch_bounds__(512, 2) void gemm10(
    const u16* __restrict__ A, const u16* __restrict__ W,
    const float* __restrict__ bias, void* __restrict__ C,
    int N, int K, int Kc, int gx, int gy)
{
  __shared__ u16 smem[65536];
  const int tid = threadIdx.x, lane = tid & 63, wid = tid >> 6;
  const int wm = wid >> 2, wn = wid & 3;

  const int nwg = gridDim.x, bid = blockIdx.x;
  const int swz = (bid & 7) * (nwg >> 3) + (bid >> 3);
  const int gxy = gx * gy;
  const int bz = swz / gxy;
  const int rem = swz - bz * gxy;
  const int by = rem / gx;
  const int bx = rem - by * gx;
  const int k0 = bz * Kc;
  const int NT = Kc >> 6;   // even, >= 4 for all our shapes
  const int NI = NT >> 1;

  const int arow = (wid >> 1) * 16 + (lane & 15);
  const int akk  = (wid & 1) * 32 + ((lane >> 4) << 3);
  const u16* gA = A + (size_t)(by * 256 + arow) * K + k0 + akk;
  const u16* gB = W + (size_t)(bx * 256 + arow) * K + k0 + akk;
  u16* ldst = smem + tid * 8;

  auto stageA = [&](int t, int h) {
    u16* d = ldst + (t & 1) * 32768 + h * 8192;
    const u16* s = gA + (size_t)(h * 128) * K + t * 64;
    GLD_LDS16(s, d);
    GLD_LDS16(s + (size_t)64 * K, d + 4096);
  };
  auto stageB = [&](int t, int h) {
    u16* d = ldst + (t & 1) * 32768 + (2 + h) * 8192;
    const u16* s = gB + (size_t)(h * 128) * K + t * 64;
    GLD_LDS16(s, d);
    GLD_LDS16(s + (size_t)64 * K, d + 4096);
  };

  v4f acc[8][4];
  #pragma unroll
  for (int i = 0; i < 8; ++i)
    #pragma unroll
    for (int j = 0; j < 4; ++j) acc[i][j] = (v4f){0.f, 0.f, 0.f, 0.f};

  // prologue: stage steps 0 and 1 fully; drain; pre-read p0 operands
  stageA(0, 0); stageA(0, 1); stageB(0, 0); stageB(0, 1);
  stageA(1, 0); stageA(1, 1); stageB(1, 0); stageB(1, 1);
  VMCNT(0);
  __builtin_amdgcn_s_barrier();

  const u16* rdA = smem + wm * 8192 + lane * 8;
  const u16* rdB = smem + 16384 + (wn >> 1) * 8192 + lane * 8;
  const int jb = (wn & 1) * 4;

  v8bf aq[4][2];        // current A-half fragments (rotated)
  v8bf bq[2][2][2];     // both B quadrant-pairs resident

#define READ_A(HALF, BO)                                                        \
  do { _Pragma("unroll") for (int m = 0; m < 4; ++m)                            \
         _Pragma("unroll") for (int kk = 0; kk < 2; ++kk)                       \
           aq[m][kk] = *(const v8bf*)(rdA + (BO) + (((HALF)*4 + m)*2 + kk)*512);\
  } while (0)
#define READ_B(QJ, BO)                                                          \
  do { _Pragma("unroll") for (int n = 0; n < 2; ++n)                            \
         _Pragma("unroll") for (int kk = 0; kk < 2; ++kk)                       \
           bq[QJ][n][kk] = *(const v8bf*)(rdB + (BO) + ((jb + (QJ)*2 + n)*2 + kk)*512); \
  } while (0)
#define MFMA_Q(QI, QJ)                                                          \
  do { __builtin_amdgcn_s_setprio(1);                                           \
       _Pragma("unroll") for (int m = 0; m < 4; ++m)                            \
         _Pragma("unroll") for (int n = 0; n < 2; ++n)                          \
           _Pragma("unroll") for (int kk = 0; kk < 2; ++kk)                     \
             acc[(QI)*4 + m][(QJ)*2 + n] =                                      \
               __builtin_amdgcn_mfma_f32_16x16x32_bf16(aq[m][kk], bq[QJ][n][kk],\
                   acc[(QI)*4 + m][(QJ)*2 + n], 0, 0, 0);                       \
       __builtin_amdgcn_s_setprio(0);                                           \
  } while (0)
#define BAR __builtin_amdgcn_s_barrier()

  READ_A(0, 0);   // A0(step0) for p0/p1
  READ_B(0, 0);   // Bq0(step0) for p0

  for (int i = 0; i < NI - 1; ++i) {
    const int t2 = 2 * i + 2, t3 = 2 * i + 3;
    // p0: (0,0) even
    LGKM0; MFMA_Q(0, 0);
    READ_B(1, 0);
    BAR;
    // p1: (0,1) even — A frag8-15 read BEFORE stageA(.,0) (WAR fix)
    LGKM0; MFMA_Q(0, 1);
    READ_A(1, 0); stageA(t2, 0); stageB(t2, 0);
    BAR;
    // p2: (1,0) even
    LGKM0; MFMA_Q(1, 0); VMCNT(6);
    READ_B(0, 32768); stageB(t2, 1);
    BAR;
    // p3: (1,1) even
    LGKM0; MFMA_Q(1, 1); VMCNT(6);
    READ_A(0, 32768); stageA(t2, 1);
    BAR;
    // p4: (0,0) odd
    LGKM0; MFMA_Q(0, 0);
    READ_B(1, 32768);
    BAR;
    // p5: (0,1) odd — same WAR fix
    LGKM0; MFMA_Q(0, 1);
    READ_A(1, 32768); stageA(t3, 0); stageB(t3, 0);
    BAR;
    // p6: (1,0) odd
    LGKM0; MFMA_Q(1, 0); VMCNT(6);
    READ_B(0, 0); stageB(t3, 1);
    BAR;
    // p7: (1,1) odd
    LGKM0; MFMA_Q(1, 1); VMCNT(6);
    READ_A(0, 0); stageA(t3, 1);
    BAR;
  }
  // peeled final iteration (steps NT-2, NT-1): no stages; drain once at p2
  LGKM0; MFMA_Q(0, 0); READ_B(1, 0); BAR;
  LGKM0; MFMA_Q(0, 1); READ_A(1, 0); BAR;
  LGKM0; MFMA_Q(1, 0); VMCNT(0); READ_B(0, 32768); BAR;
  LGKM0; MFMA_Q(1, 1); READ_A(0, 32768); BAR;
  LGKM0; MFMA_Q(0, 0); READ_B(1, 32768); BAR;
  LGKM0; MFMA_Q(0, 1); READ_A(1, 32768); BAR;
  LGKM0; MFMA_Q(1, 0); BAR;
  LGKM0; MFMA_Q(1, 1);
#undef READ_A
#undef READ_B
#undef MFMA_Q
#undef BAR

  const int cn0 = bx * 256 + wn * 64 + (lane & 15);
  const int rm0 = by * 256 + wm * 128 + ((lane >> 4) << 2);
  if (FUSE == 2) {
    u16* Cp = (u16*)C + (size_t)bz * 4096 * N;
    #pragma unroll
    for (int i = 0; i < 8; ++i)
      #pragma unroll
      for (int r = 0; r < 4; ++r) {
        size_t ro = (size_t)(rm0 + i * 16 + r) * N + cn0;
        #pragma unroll
        for (int j = 0; j < 4; ++j) Cp[ro + j * 16] = f2bf(acc[i][j][r]);
      }
  } else {
    float bv[4];
    #pragma unroll
    for (int j = 0; j < 4; ++j) bv[j] = bias[cn0 + j * 16];
    u16* Cp = (u16*)C;
    #pragma unroll
    for (int i = 0; i < 8; ++i)
      #pragma unroll
      for (int r = 0; r < 4; ++r) {
        size_t ro = (size_t)(rm0 + i * 16 + r) * N + cn0;
        #pragma unroll
        for (int j = 0; j < 4; ++j) {
          float v = acc[i][j][r] + bv[j];
          if (FUSE == 1) v = fmaxf(v, 0.f);
          Cp[ro + j * 16] = f2bf(v);
        }
      }
  }
}

// ---------------------------------------------------------------------------
// attn_f (unchanged, verified R11)
// ---------------------------------------------------------------------------
__global__ __launch_bounds__(256, 2) void attn_f(const u16* __restrict__ qkv,
                                                 u16* __restrict__ o)
{
  __shared__ u16 Kf[2][4096];
  __shared__ u16 Vt[2][4096];
  __shared__ u16 wbuf[64 * 72];
  const int tid = threadIdx.x, lane = tid & 63, wid = tid >> 6;
  const int grp = lane >> 4, li = lane & 15;
  const int bh = blockIdx.y, b = bh >> 4, h = bh & 15;
  const int q0 = blockIdx.x * 64;
  const u16* Qg = qkv + (size_t)b * 512 * 3072 + h * 64;
  const u16* Kg = Qg + 1024;
  const u16* Vg = Qg + 2048;

  const size_t qrow = (size_t)(q0 + wid * 16 + li) * 3072;
  v8bf qa0 = *(const v8bf*)(Qg + qrow + grp * 8);
  v8bf qa1 = *(const v8bf*)(Qg + qrow + 32 + grp * 8);

  const u16* kga = Kg + (size_t)(wid * 16 + li) * 3072 + grp * 8;
  auto k_stage = [&](int kt, int buf) {
    #pragma unroll
    for (int s = 0; s < 2; ++s)
      GLD_LDS16(kga + (size_t)kt * 64 * 3072 + s * 32, &Kf[buf][(wid * 2 + s) * 512]);
  };
  auto v_load = [&](int kt, int x) -> v8bf {
    int u = x * 256 + tid, kk = u >> 3, d0 = (u & 7) * 8;
    return *(const v8bf*)(Vg + (size_t)(kt * 64 + kk) * 3072 + d0);
  };
  auto vt_write = [&](int buf, int x, v8bf v) {
    int u = x * 256 + tid, kk = u >> 3, d0 = (u & 7) * 8;
    int kg = (kk >> 3) & 3, kks = kk >> 5, jb2 = (kk & 7) * 2;
    #pragma unroll
    for (int i = 0; i < 8; ++i) {
      int d = d0 + i;
      int byte = (((d >> 4) * 2 + kks) * 1024 + ((d & 15) + 16 * kg) * 16 + jb2)
                 ^ (((d >> 4) & 3) << 5);
      *(u16*)((char*)&Vt[buf][0] + byte) = (u16)v[i];
    }
  };

  v4f oacc[4];
  #pragma unroll
  for (int nt = 0; nt < 4; ++nt) oacc[nt] = (v4f){0.f, 0.f, 0.f, 0.f};
  float mreg[4] = {-1e30f, -1e30f, -1e30f, -1e30f};
  float sgl[4] = {0.f, 0.f, 0.f, 0.f};
  float fqv[4];
  #pragma unroll
  for (int j = 0; j < 4; ++j) fqv[j] = (float)(q0 + wid * 16 + grp * 4 + j);

  v8bf vst[2][2];
  k_stage(0, 0);
  k_stage(1, 1);
  vst[0][0] = v_load(0, 0); vst[0][1] = v_load(0, 1);
  VMCNT(0);
  vt_write(0, 0, vst[0][0]); vt_write(0, 1, vst[0][1]);
  vst[1][0] = v_load(1, 0); vst[1][1] = v_load(1, 1);
  LGKM0;
  __builtin_amdgcn_s_barrier();

  const float SC2 = 0.18033688011112042f;    // 0.125 * log2(e)
  const float GC2 = 4.4027559280058695e-05f; // log2(e) / 32768

  #pragma unroll
  for (int t = 0; t < 8; ++t) {
    const int cur = t & 1;
    v8bf bq0[4], bq1[4];
    #pragma unroll
    for (int nb = 0; nb < 4; ++nb) {
      bq0[nb] = *(const v8bf*)&Kf[cur][(nb * 2 + 0) * 512 + lane * 8];
      bq1[nb] = *(const v8bf*)&Kf[cur][(nb * 2 + 1) * 512 + lane * 8];
    }
    v4f pa[4];
    #pragma unroll
    for (int nb = 0; nb < 4; ++nb) {
      v4f z = (v4f){0.f, 0.f, 0.f, 0.f};
      z = __builtin_amdgcn_mfma_f32_16x16x32_bf16(qa0, bq0[nb], z, 0, 0, 0);
      pa[nb] = __builtin_amdgcn_mfma_f32_16x16x32_bf16(qa1, bq1[nb], z, 0, 0, 0);
    }
    if (t < 7) {
      __builtin_amdgcn_s_barrier();
      __builtin_amdgcn_sched_barrier(0);
      if (t + 2 < 8) k_stage(t + 2, cur);
      if (t < 6) { VMCNT(2); } else { VMCNT(0); }
      vt_write((t + 1) & 1, 0, vst[(t + 1) & 1][0]);
      vt_write((t + 1) & 1, 1, vst[(t + 1) & 1][1]);
      if (t + 2 < 8) { vst[t & 1][0] = v_load(t + 2, 0); vst[t & 1][1] = v_load(t + 2, 1); }
    }
    #pragma unroll
    for (int nb = 0; nb < 4; ++nb) {
      const float fk = (float)(t * 64 + nb * 16 + li);
      #pragma unroll
      for (int j = 0; j < 4; ++j) {
        float d = fqv[j] - fk;
        pa[nb][j] = pa[nb][j] * SC2 - d * d * GC2;
      }
    }
    float rel = -1e30f;
    #pragma unroll
    for (int j = 0; j < 4; ++j)
      #pragma unroll
      for (int nb = 0; nb < 4; ++nb)
        rel = fmaxf(rel, pa[nb][j] - mreg[j]);
    if (!__all(rel <= 11.0f)) {
      #pragma unroll
      for (int j = 0; j < 4; ++j) {
        float tmax = fmaxf(fmaxf(pa[0][j], pa[1][j]), fmaxf(pa[2][j], pa[3][j]));
        tmax = fmaxf(tmax, __shfl_xor(tmax, 1));
        tmax = fmaxf(tmax, __shfl_xor(tmax, 2));
        tmax = fmaxf(tmax, __shfl_xor(tmax, 4));
        tmax = fmaxf(tmax, __shfl_xor(tmax, 8));
        float mn = fmaxf(mreg[j], tmax);
        float sc = ex2(mreg[j] - mn);
        mreg[j] = mn;
        sgl[j] *= sc;
        #pragma unroll
        for (int nt = 0; nt < 4; ++nt) oacc[nt][j] *= sc;
      }
    }
    #pragma unroll
    for (int j = 0; j < 4; ++j) {
      #pragma unroll
      for (int nb = 0; nb < 4; ++nb) {
        float e = ex2(pa[nb][j] - mreg[j]);
        pa[nb][j] = e;
        sgl[j] += e;
      }
    }
    #pragma unroll
    for (int j = 0; j < 4; ++j) {
      const int row = wid * 16 + grp * 4 + j;
      #pragma unroll
      for (int nb = 0; nb < 4; ++nb) {
        union { float f; unsigned u; } cv; cv.f = pa[nb][j];
        wbuf[row * 72 + ((nb * 16 + li) ^ (grp << 3))] = (u16)(cv.u >> 16);
      }
    }
    const int swr = ((li >> 2) & 3) << 3;
    v8bf af0 = *(const v8bf*)&wbuf[(wid * 16 + li) * 72 + ((0 * 32 + grp * 8) ^ swr)];
    v8bf af1 = *(const v8bf*)&wbuf[(wid * 16 + li) * 72 + ((1 * 32 + grp * 8) ^ swr)];
    #pragma unroll
    for (int nt = 0; nt < 4; ++nt) {
      v8bf bv0 = *(const v8bf*)((char*)&Vt[cur][0] + ((((nt * 2 + 0) * 1024) + lane * 16) ^ ((nt & 3) << 5)));
      v8bf bv1 = *(const v8bf*)((char*)&Vt[cur][0] + ((((nt * 2 + 1) * 1024) + lane * 16) ^ ((nt & 3) << 5)));
      oacc[nt] = __builtin_amdgcn_mfma_f32_16x16x32_bf16(af0, bv0, oacc[nt], 0, 0, 0);
      oacc[nt] = __builtin_amdgcn_mfma_f32_16x16x32_bf16(af1, bv1, oacc[nt], 0, 0, 0);
    }
    if (t < 7) {
      if (t < 6) { VMCNT(2); } else { VMCNT(0); }
      LGKM0;
      __builtin_amdgcn_s_barrier();
      __builtin_amdgcn_sched_barrier(0);
    }
  }

  float rin[4];
  #pragma unroll
  for (int j = 0; j < 4; ++j) {
    float s = sgl[j];
    s += __shfl_xor(s, 1); s += __shfl_xor(s, 2);
    s += __shfl_xor(s, 4); s += __shfl_xor(s, 8);
    rin[j] = 1.f / s;
  }
  const size_t obase = (size_t)(b * 512 + q0 + wid * 16 + grp * 4) * 1024 + h * 64;
  #pragma unroll
  for (int nt = 0; nt < 4; ++nt)
    #pragma unroll
    for (int j = 0; j < 4; ++j)
      o[obase + (size_t)j * 1024 + nt * 16 + li] = f2bf(oacc[nt][j] * rin[j]);
}

// ---------------------------------------------------------------------------
// LayerNorm(xb + bias + sum of 4 bf16 partials) * g + beta -> xb (bf16 master)
// ---------------------------------------------------------------------------
__global__ __launch_bounds__(256) void ln_res4_k(
    const u16* __restrict__ x, const u16* __restrict__ part,
    const float* __restrict__ bias, const float* __restrict__ g,
    const float* __restrict__ beta, u16* __restrict__ yb)
{
  const int row = blockIdx.x, tid = threadIdx.x;
  const size_t base = (size_t)row * 1024 + tid * 4;
  const size_t MN = 4096ull * 1024;
  ushort4 xv = *(const ushort4*)(x + base);
  const int e = tid * 4;
  float4 bb = *(const float4*)(bias + e);
  float v0 = bf2f(xv.x) + bb.x, v1 = bf2f(xv.y) + bb.y;
  float v2 = bf2f(xv.z) + bb.z, v3 = bf2f(xv.w) + bb.w;
  #pragma unroll
  for (int q = 0; q < 4; ++q) {
    ushort4 pv = *(const ushort4*)(part + q * MN + base);
    v0 += bf2f(pv.x); v1 += bf2f(pv.y); v2 += bf2f(pv.z); v3 += bf2f(pv.w);
  }
  float s = v0 + v1 + v2 + v3;
  float q2 = v0*v0 + v1*v1 + v2*v2 + v3*v3;
  #pragma unroll
  for (int m = 1; m < 64; m <<= 1) { s += __shfl_xor(s, m); q2 += __shfl_xor(q2, m); }
  __shared__ float ls[4], lq[4];
  if ((tid & 63) == 0) { ls[tid >> 6] = s; lq[tid >> 6] = q2; }
  __syncthreads();
  s = ls[0] + ls[1] + ls[2] + ls[3];
  q2 = lq[0] + lq[1] + lq[2] + lq[3];
  const float mu = s * (1.f / 1024.f);
  const float var = q2 * (1.f / 1024.f) - mu * mu;
  const float rs = rsqrtf(var + 1e-5f);
  float4 gv = *(const float4*)(g + e);
  float4 be = *(const float4*)(beta + e);
  float o0 = (v0 - mu) * rs * gv.x + be.x;
  float o1 = (v1 - mu) * rs * gv.y + be.y;
  float o2 = (v2 - mu) * rs * gv.z + be.z;
  float o3 = (v3 - mu) * rs * gv.w + be.w;
  ushort4 ob; ob.x = f2bf(o0); ob.y = f2bf(o1); ob.z = f2bf(o2); ob.w = f2bf(o3);
  *(ushort4*)(yb + base) = ob;
}

// x = src + pe(batch, e), vectorized x4 (1048576 float4 units -> 4096 blocks)
__global__ __launch_bounds__(256) void pe_add_k(const float* __restrict__ src,
    u16* __restrict__ xb)
{
  const int u = blockIdx.x * 256 + threadIdx.x;
  const int e4 = (u & 255) * 4;
  const int b = u >> 17;
  const float C = -18.420680743952367f * (1.f / 1024.f);
  float4 sv = ((const float4*)src)[u];
  float fb = (float)b;
  float fr0 = __expf((float)(e4 >> 1) * C);
  float fr1 = __expf((float)((e4 >> 1) + 1) * C);
  float a0 = fb * fr0, a1 = fb * fr1;
  ushort4 ov;
  ov.x = f2bf(sv.x + __sinf(a0));
  ov.y = f2bf(sv.y + __cosf(a0));
  ov.z = f2bf(sv.z + __sinf(a1));
  ov.w = f2bf(sv.w + __cosf(a1));
  ((ushort4*)xb)[u] = ov;
}

__global__ __launch_bounds__(256) void cvt4_k(const float* __restrict__ s0,
    const float* __restrict__ s1, const float* __restrict__ s2,
    const float* __restrict__ s3, u16* __restrict__ dst)
{
  int i = blockIdx.x * 256 + threadIdx.x;
  const float* s; size_t off;
  if (i < 786432)       { s = s0; off = (size_t)i; }
  else if (i < 1048576) { s = s1; off = (size_t)i - 786432; }
  else if (i < 2097152) { s = s2; off = (size_t)i - 1048576; }
  else                  { s = s3; off = (size_t)i - 2097152; }
  float4 v = ((const float4*)s)[off];
  ushort4 ov; ov.x = f2bf(v.x); ov.y = f2bf(v.y); ov.z = f2bf(v.z); ov.w = f2bf(v.w);
  ((ushort4*)dst)[i] = ov;
}

__global__ __launch_bounds__(256) void head_k(const u16* __restrict__ xb,
    const float* __restrict__ hw, const float* __restrict__ hb, float* __restrict__ out)
{
  const int b = blockIdx.x, tid = threadIdx.x;
  const ushort4 xv = ((const ushort4*)(xb + ((size_t)b * 512 + 511) * 1024))[tid];
  const float4 wv = ((const float4*)hw)[tid];
  float s = bf2f(xv.x) * wv.x + bf2f(xv.y) * wv.y + bf2f(xv.z) * wv.z + bf2f(xv.w) * wv.w;
  #pragma unroll
  for (int m = 1; m < 64; m <<= 1) s += __shfl_xor(s, m);
  __shared__ float ls[4];
  if ((tid & 63) == 0) ls[tid >> 6] = s;
  __syncthreads();
  if (tid == 0) out[b] = ls[0] + ls[1] + ls[2] + ls[3] + hb[0];
}

// ---------------------------------------------------------------------------
extern "C" void kernel_launch(void* const* d_in, const int* in_sizes, int n_in,
                              void* d_out, int out_size, void* d_ws, size_t ws_size,
                              hipStream_t stream)
{
  const float* src  = (const float*)d_in[0];
  const float* ipw  = (const float*)d_in[1];
  const float* ipb  = (const float*)d_in[2];
  const float* outw = (const float*)d_in[3];
  const float* outb = (const float*)d_in[4];
  const float* f1w  = (const float*)d_in[5];
  const float* f1b  = (const float*)d_in[6];
  const float* f2w  = (const float*)d_in[7];
  const float* f2b  = (const float*)d_in[8];
  const float* l1g  = (const float*)d_in[9];
  const float* l1b  = (const float*)d_in[10];
  const float* l2g  = (const float*)d_in[11];
  const float* l2b  = (const float*)d_in[12];
  const float* hw   = (const float*)d_in[13];
  const float* hb   = (const float*)d_in[14];

  char* p = (char*)d_ws;
  auto take = [&](size_t bytes) { char* r = p; p += (bytes + 255) & ~(size_t)255; return r; };
  u16*   xb   = (u16*)  take(4096ull * 1024 * 2);
  u16*   slA  = (u16*)  take(4096ull * 4096 * 2);
  u16*   ob   = (u16*)  take(4096ull * 1024 * 2);
  u16*   pf   = (u16*)  take(4ull * 4096 * 1024 * 2);
  u16*   wc   = (u16*)  take(12582912ull * 2);

  u16* qkvb = slA;
  u16* f1o  = slA;

  pe_add_k<<<4096, 256, 0, stream>>>(src, xb);

  for (int l = 0; l < 4; ++l) {
    cvt4_k<<<12288, 256, 0, stream>>>(ipw + (size_t)l * 3145728,
                                      outw + (size_t)l * 1048576,
                                      f1w + (size_t)l * 4194304,
                                      f2w + (size_t)l * 4194304, wc);
    // QKV: [4096,3072], K=1024
    gemm10<0><<<192, 512, 0, stream>>>(xb, wc, ipb + l * 3072, qkvb, 3072, 1024, 1024, 12, 16);
    attn_f<<<dim3(8, 128), 256, 0, stream>>>(qkvb, ob);
    // out-proj: N=1024, K=1024, split-K=4
    gemm10<2><<<256, 512, 0, stream>>>(ob, wc + 3145728, nullptr, pf, 1024, 1024, 256, 4, 16);
    ln_res4_k<<<4096, 256, 0, stream>>>(xb, pf, outb + l * 1024, l1g + l * 1024, l1b + l * 1024, xb);
    // FF1: [4096,4096], K=1024, ReLU
    gemm10<1><<<256, 512, 0, stream>>>(xb, wc + 4194304, f1b + l * 4096, f1o, 4096, 1024, 1024, 16, 16);
    // FF2: N=1024, K=4096, split-K=4
    gemm10<2><<<256, 512, 0, stream>>>(f1o, wc + 8388608, nullptr, pf, 1024, 4096, 1024, 4, 16);
    ln_res4_k<<<4096, 256, 0, stream>>>(xb, pf, f2b + l * 1024, l2g + l * 1024, l2b + l * 1024, xb);
  }
  head_k<<<8, 256, 0, stream>>>(xb, hw, hb, (float*)d_out);
}

// Round 14
// 798.505 us; speedup vs baseline: 1.2927x; 1.2927x over previous
//
#include <hip/hip_runtime.h>

typedef unsigned short u16;
typedef __attribute__((ext_vector_type(4))) float v4f;
typedef __attribute__((ext_vector_type(8))) short v8bf;

extern "C" __device__ float __ocml_native_exp2_f32(float);  // bare v_exp_f32
__device__ inline float ex2(float x){ return __ocml_native_exp2_f32(x); }

__device__ inline u16 f2bf(float f){
  union { float f; unsigned u; } v; v.f = f;
  unsigned r = (v.u + 0x7FFFu + ((v.u >> 16) & 1u)) >> 16;
  return (u16)r;
}
__device__ inline float bf2f(u16 u){
  union { unsigned u; float f; } v; v.u = ((unsigned)u) << 16;
  return v.f;
}

#define GLD_LDS16(gp, lp) \
  __builtin_amdgcn_global_load_lds((const __attribute__((address_space(1))) void*)(gp), \
                                   (__attribute__((address_space(3))) void*)(lp), 16, 0, 0)
#define VMCNT(n) asm volatile("s_waitcnt vmcnt(" #n ")" ::: "memory")
#define LGKM0 do { asm volatile("s_waitcnt lgkmcnt(0)" ::: "memory"); \
                   __builtin_amdgcn_sched_barrier(0); } while (0)

// ---------------------------------------------------------------------------
// gemm9 (verified R7/R11 schedule): 256x256 tile, BK=64, 3 barriers/tile,
// compiler fine-grained lgkm, counted vmcnt(4).
// FUSE: 0 = bf16+bias, 1 = bf16+bias+ReLU, 2 = bf16 split-K partial (no bias)
// ---------------------------------------------------------------------------
template<int FUSE>
__global__ __launch_bounds__(512, 2) void gemm9(
    const u16* __restrict__ A, const u16* __restrict__ W,
    const float* __restrict__ bias, void* __restrict__ C,
    int N, int K, int Kc, int gx, int gy)
{
  __shared__ u16 smem[65536];
  const int tid = threadIdx.x, lane = tid & 63, wid = tid >> 6;
  const int wm = wid >> 2, wn = wid & 3;

  const int nwg = gridDim.x, bid = blockIdx.x;
  const int swz = (bid & 7) * (nwg >> 3) + (bid >> 3);
  const int gxy = gx * gy;
  const int bz = swz / gxy;
  const int rem = swz - bz * gxy;
  const int by = rem / gx;
  const int bx = rem - by * gx;
  const int k0 = bz * Kc;
  const int NT = Kc >> 6;

  const int arow = (wid >> 1) * 16 + (lane & 15);
  const int akk  = (wid & 1) * 32 + ((lane >> 4) << 3);
  const u16* gA = A + (size_t)(by * 256 + arow) * K + k0 + akk;
  const u16* gB = W + (size_t)(bx * 256 + arow) * K + k0 + akk;
  u16* ldst = smem + tid * 8;

  auto stageA = [&](int t, int h) {
    u16* d = ldst + (t & 1) * 32768 + h * 8192;
    const u16* s = gA + (size_t)(h * 128) * K + t * 64;
    GLD_LDS16(s, d);
    GLD_LDS16(s + (size_t)64 * K, d + 4096);
  };
  auto stageB = [&](int t, int h) {
    u16* d = ldst + (t & 1) * 32768 + (2 + h) * 8192;
    const u16* s = gB + (size_t)(h * 128) * K + t * 64;
    GLD_LDS16(s, d);
    GLD_LDS16(s + (size_t)64 * K, d + 4096);
  };

  v4f acc[8][4];
  #pragma unroll
  for (int i = 0; i < 8; ++i)
    #pragma unroll
    for (int j = 0; j < 4; ++j) acc[i][j] = (v4f){0.f, 0.f, 0.f, 0.f};

  stageA(0, 0); stageA(0, 1); stageB(0, 0); stageB(0, 1);
  if (NT > 1) { stageA(1, 0); stageA(1, 1); VMCNT(4); } else { VMCNT(0); }
  __builtin_amdgcn_s_barrier();

  const u16* rdA = smem + wm * 8192 + lane * 8;
  const u16* rdB = smem + 16384 + (wn >> 1) * 8192 + lane * 8;
  const int jb = (wn & 1) * 4;

  v8bf aq[4][2], bq[4][2];

#define MFMA_CL(QI, NLO)                                                        \
  do {                                                                          \
    __builtin_amdgcn_s_setprio(1);                                              \
    _Pragma("unroll") for (int m = 0; m < 4; ++m)                               \
      _Pragma("unroll") for (int n = NLO; n < NLO + 2; ++n)                     \
        _Pragma("unroll") for (int kk = 0; kk < 2; ++kk)                        \
          acc[(QI)*4 + m][n] = __builtin_amdgcn_mfma_f32_16x16x32_bf16(         \
              aq[m][kk], bq[n][kk], acc[(QI)*4 + m][n], 0, 0, 0);               \
    __builtin_amdgcn_s_setprio(0);                                              \
  } while (0)

  for (int t = 0; t < NT; ++t) {
    const int bufo = (t & 1) * 32768;
    __builtin_amdgcn_sched_barrier(0);
    #pragma unroll
    for (int m = 0; m < 4; ++m)
      #pragma unroll
      for (int kk = 0; kk < 2; ++kk)
        aq[m][kk] = *(const v8bf*)(rdA + bufo + (m * 2 + kk) * 512);
    #pragma unroll
    for (int n = 0; n < 2; ++n)
      #pragma unroll
      for (int kk = 0; kk < 2; ++kk)
        bq[n][kk] = *(const v8bf*)(rdB + bufo + ((jb + n) * 2 + kk) * 512);
    if (t + 1 < NT) stageB(t + 1, 0);
    MFMA_CL(0, 0);
    #pragma unroll
    for (int n = 2; n < 4; ++n)
      #pragma unroll
      for (int kk = 0; kk < 2; ++kk)
        bq[n][kk] = *(const v8bf*)(rdB + bufo + ((jb + n) * 2 + kk) * 512);
    if (t + 1 < NT) stageB(t + 1, 1);
    MFMA_CL(0, 2);
    __builtin_amdgcn_s_barrier();
    __builtin_amdgcn_sched_barrier(0);
    #pragma unroll
    for (int m = 0; m < 4; ++m)
      #pragma unroll
      for (int kk = 0; kk < 2; ++kk)
        aq[m][kk] = *(const v8bf*)(rdA + bufo + ((4 + m) * 2 + kk) * 512);
    if (t + 2 < NT) stageA(t + 2, 0);
    MFMA_CL(1, 2);
    __builtin_amdgcn_s_barrier();
    __builtin_amdgcn_sched_barrier(0);
    if (t + 2 < NT) stageA(t + 2, 1);
    MFMA_CL(1, 0);
    if (t < NT - 2) { VMCNT(4); } else if (t == NT - 2) { VMCNT(0); }
    __builtin_amdgcn_s_barrier();
  }
#undef MFMA_CL

  const int cn0 = bx * 256 + wn * 64 + (lane & 15);
  const int rm0 = by * 256 + wm * 128 + ((lane >> 4) << 2);
  if (FUSE == 2) {
    u16* Cp = (u16*)C + (size_t)bz * 4096 * N;
    #pragma unroll
    for (int i = 0; i < 8; ++i)
      #pragma unroll
      for (int r = 0; r < 4; ++r) {
        size_t ro = (size_t)(rm0 + i * 16 + r) * N + cn0;
        #pragma unroll
        for (int j = 0; j < 4; ++j) Cp[ro + j * 16] = f2bf(acc[i][j][r]);
      }
  } else {
    float bv[4];
    #pragma unroll
    for (int j = 0; j < 4; ++j) bv[j] = bias[cn0 + j * 16];
    u16* Cp = (u16*)C;
    #pragma unroll
    for (int i = 0; i < 8; ++i)
      #pragma unroll
      for (int r = 0; r < 4; ++r) {
        size_t ro = (size_t)(rm0 + i * 16 + r) * N + cn0;
        #pragma unroll
        for (int j = 0; j < 4; ++j) {
          float v = acc[i][j][r] + bv[j];
          if (FUSE == 1) v = fmaxf(v, 0.f);
          Cp[ro + j * 16] = f2bf(v);
        }
      }
  }
}

// ---------------------------------------------------------------------------
// attn_f (R11 body) + R14 XCD-locality swizzle: 1-D grid 1024,
// bh = id & 127, qb = id >> 7 -> all 8 q-blocks of one (b,h) share an XCD.
// ---------------------------------------------------------------------------
__global__ __launch_bounds__(256, 2) void attn_f(const u16* __restrict__ qkv,
                                                 u16* __restrict__ o)
{
  __shared__ u16 Kf[2][4096];
  __shared__ u16 Vt[2][4096];
  __shared__ u16 wbuf[64 * 72];
  const int tid = threadIdx.x, lane = tid & 63, wid = tid >> 6;
  const int grp = lane >> 4, li = lane & 15;
  const int id = blockIdx.x;
  const int bh = id & 127, b = bh >> 4, h = bh & 15;
  const int q0 = (id >> 7) * 64;
  const u16* Qg = qkv + (size_t)b * 512 * 3072 + h * 64;
  const u16* Kg = Qg + 1024;
  const u16* Vg = Qg + 2048;

  const size_t qrow = (size_t)(q0 + wid * 16 + li) * 3072;
  v8bf qa0 = *(const v8bf*)(Qg + qrow + grp * 8);
  v8bf qa1 = *(const v8bf*)(Qg + qrow + 32 + grp * 8);

  const u16* kga = Kg + (size_t)(wid * 16 + li) * 3072 + grp * 8;
  auto k_stage = [&](int kt, int buf) {
    #pragma unroll
    for (int s = 0; s < 2; ++s)
      GLD_LDS16(kga + (size_t)kt * 64 * 3072 + s * 32, &Kf[buf][(wid * 2 + s) * 512]);
  };
  auto v_load = [&](int kt, int x) -> v8bf {
    int u = x * 256 + tid, kk = u >> 3, d0 = (u & 7) * 8;
    return *(const v8bf*)(Vg + (size_t)(kt * 64 + kk) * 3072 + d0);
  };
  auto vt_write = [&](int buf, int x, v8bf v) {
    int u = x * 256 + tid, kk = u >> 3, d0 = (u & 7) * 8;
    int kg = (kk >> 3) & 3, kks = kk >> 5, jb2 = (kk & 7) * 2;
    #pragma unroll
    for (int i = 0; i < 8; ++i) {
      int d = d0 + i;
      int byte = (((d >> 4) * 2 + kks) * 1024 + ((d & 15) + 16 * kg) * 16 + jb2)
                 ^ (((d >> 4) & 3) << 5);
      *(u16*)((char*)&Vt[buf][0] + byte) = (u16)v[i];
    }
  };

  v4f oacc[4];
  #pragma unroll
  for (int nt = 0; nt < 4; ++nt) oacc[nt] = (v4f){0.f, 0.f, 0.f, 0.f};
  float mreg[4] = {-1e30f, -1e30f, -1e30f, -1e30f};
  float sgl[4] = {0.f, 0.f, 0.f, 0.f};
  float fqv[4];
  #pragma unroll
  for (int j = 0; j < 4; ++j) fqv[j] = (float)(q0 + wid * 16 + grp * 4 + j);

  v8bf vst[2][2];
  k_stage(0, 0);
  k_stage(1, 1);
  vst[0][0] = v_load(0, 0); vst[0][1] = v_load(0, 1);
  VMCNT(0);
  vt_write(0, 0, vst[0][0]); vt_write(0, 1, vst[0][1]);
  vst[1][0] = v_load(1, 0); vst[1][1] = v_load(1, 1);
  LGKM0;
  __builtin_amdgcn_s_barrier();

  const float SC2 = 0.18033688011112042f;    // 0.125 * log2(e)
  const float GC2 = 4.4027559280058695e-05f; // log2(e) / 32768

  #pragma unroll
  for (int t = 0; t < 8; ++t) {
    const int cur = t & 1;
    v8bf bq0[4], bq1[4];
    #pragma unroll
    for (int nb = 0; nb < 4; ++nb) {
      bq0[nb] = *(const v8bf*)&Kf[cur][(nb * 2 + 0) * 512 + lane * 8];
      bq1[nb] = *(const v8bf*)&Kf[cur][(nb * 2 + 1) * 512 + lane * 8];
    }
    v4f pa[4];
    #pragma unroll
    for (int nb = 0; nb < 4; ++nb) {
      v4f z = (v4f){0.f, 0.f, 0.f, 0.f};
      z = __builtin_amdgcn_mfma_f32_16x16x32_bf16(qa0, bq0[nb], z, 0, 0, 0);
      pa[nb] = __builtin_amdgcn_mfma_f32_16x16x32_bf16(qa1, bq1[nb], z, 0, 0, 0);
    }
    if (t < 7) {
      __builtin_amdgcn_s_barrier();
      __builtin_amdgcn_sched_barrier(0);
      if (t + 2 < 8) k_stage(t + 2, cur);
      if (t < 6) { VMCNT(2); } else { VMCNT(0); }
      vt_write((t + 1) & 1, 0, vst[(t + 1) & 1][0]);
      vt_write((t + 1) & 1, 1, vst[(t + 1) & 1][1]);
      if (t + 2 < 8) { vst[t & 1][0] = v_load(t + 2, 0); vst[t & 1][1] = v_load(t + 2, 1); }
    }
    #pragma unroll
    for (int nb = 0; nb < 4; ++nb) {
      const float fk = (float)(t * 64 + nb * 16 + li);
      #pragma unroll
      for (int j = 0; j < 4; ++j) {
        float d = fqv[j] - fk;
        pa[nb][j] = pa[nb][j] * SC2 - d * d * GC2;
      }
    }
    float rel = -1e30f;
    #pragma unroll
    for (int j = 0; j < 4; ++j)
      #pragma unroll
      for (int nb = 0; nb < 4; ++nb)
        rel = fmaxf(rel, pa[nb][j] - mreg[j]);
    if (!__all(rel <= 11.0f)) {
      #pragma unroll
      for (int j = 0; j < 4; ++j) {
        float tmax = fmaxf(fmaxf(pa[0][j], pa[1][j]), fmaxf(pa[2][j], pa[3][j]));
        tmax = fmaxf(tmax, __shfl_xor(tmax, 1));
        tmax = fmaxf(tmax, __shfl_xor(tmax, 2));
        tmax = fmaxf(tmax, __shfl_xor(tmax, 4));
        tmax = fmaxf(tmax, __shfl_xor(tmax, 8));
        float mn = fmaxf(mreg[j], tmax);
        float sc = ex2(mreg[j] - mn);
        mreg[j] = mn;
        sgl[j] *= sc;
        #pragma unroll
        for (int nt = 0; nt < 4; ++nt) oacc[nt][j] *= sc;
      }
    }
    #pragma unroll
    for (int j = 0; j < 4; ++j) {
      #pragma unroll
      for (int nb = 0; nb < 4; ++nb) {
        float e = ex2(pa[nb][j] - mreg[j]);
        pa[nb][j] = e;
        sgl[j] += e;
      }
    }
    #pragma unroll
    for (int j = 0; j < 4; ++j) {
      const int row = wid * 16 + grp * 4 + j;
      #pragma unroll
      for (int nb = 0; nb < 4; ++nb) {
        union { float f; unsigned u; } cv; cv.f = pa[nb][j];
        wbuf[row * 72 + ((nb * 16 + li) ^ (grp << 3))] = (u16)(cv.u >> 16);
      }
    }
    const int swr = ((li >> 2) & 3) << 3;
    v8bf af0 = *(const v8bf*)&wbuf[(wid * 16 + li) * 72 + ((0 * 32 + grp * 8) ^ swr)];
    v8bf af1 = *(const v8bf*)&wbuf[(wid * 16 + li) * 72 + ((1 * 32 + grp * 8) ^ swr)];
    #pragma unroll
    for (int nt = 0; nt < 4; ++nt) {
      v8bf bv0 = *(const v8bf*)((char*)&Vt[cur][0] + ((((nt * 2 + 0) * 1024) + lane * 16) ^ ((nt & 3) << 5)));
      v8bf bv1 = *(const v8bf*)((char*)&Vt[cur][0] + ((((nt * 2 + 1) * 1024) + lane * 16) ^ ((nt & 3) << 5)));
      oacc[nt] = __builtin_amdgcn_mfma_f32_16x16x32_bf16(af0, bv0, oacc[nt], 0, 0, 0);
      oacc[nt] = __builtin_amdgcn_mfma_f32_16x16x32_bf16(af1, bv1, oacc[nt], 0, 0, 0);
    }
    if (t < 7) {
      if (t < 6) { VMCNT(2); } else { VMCNT(0); }
      LGKM0;
      __builtin_amdgcn_s_barrier();
      __builtin_amdgcn_sched_barrier(0);
    }
  }

  float rin[4];
  #pragma unroll
  for (int j = 0; j < 4; ++j) {
    float s = sgl[j];
    s += __shfl_xor(s, 1); s += __shfl_xor(s, 2);
    s += __shfl_xor(s, 4); s += __shfl_xor(s, 8);
    rin[j] = 1.f / s;
  }
  const size_t obase = (size_t)(b * 512 + q0 + wid * 16 + grp * 4) * 1024 + h * 64;
  #pragma unroll
  for (int nt = 0; nt < 4; ++nt)
    #pragma unroll
    for (int j = 0; j < 4; ++j)
      o[obase + (size_t)j * 1024 + nt * 16 + li] = f2bf(oacc[nt][j] * rin[j]);
}

// ---------------------------------------------------------------------------
// LayerNorm(xb + bias + sum of 4 bf16 partials) * g + beta -> xb (bf16 master)
// ---------------------------------------------------------------------------
__global__ __launch_bounds__(256) void ln_res4_k(
    const u16* __restrict__ x, const u16* __restrict__ part,
    const float* __restrict__ bias, const float* __restrict__ g,
    const float* __restrict__ beta, u16* __restrict__ yb)
{
  const int row = blockIdx.x, tid = threadIdx.x;
  const size_t base = (size_t)row * 1024 + tid * 4;
  const size_t MN = 4096ull * 1024;
  ushort4 xv = *(const ushort4*)(x + base);
  const int e = tid * 4;
  float4 bb = *(const float4*)(bias + e);
  float v0 = bf2f(xv.x) + bb.x, v1 = bf2f(xv.y) + bb.y;
  float v2 = bf2f(xv.z) + bb.z, v3 = bf2f(xv.w) + bb.w;
  #pragma unroll
  for (int q = 0; q < 4; ++q) {
    ushort4 pv = *(const ushort4*)(part + q * MN + base);
    v0 += bf2f(pv.x); v1 += bf2f(pv.y); v2 += bf2f(pv.z); v3 += bf2f(pv.w);
  }
  float s = v0 + v1 + v2 + v3;
  float q2 = v0*v0 + v1*v1 + v2*v2 + v3*v3;
  #pragma unroll
  for (int m = 1; m < 64; m <<= 1) { s += __shfl_xor(s, m); q2 += __shfl_xor(q2, m); }
  __shared__ float ls[4], lq[4];
  if ((tid & 63) == 0) { ls[tid >> 6] = s; lq[tid >> 6] = q2; }
  __syncthreads();
  s = ls[0] + ls[1] + ls[2] + ls[3];
  q2 = lq[0] + lq[1] + lq[2] + lq[3];
  const float mu = s * (1.f / 1024.f);
  const float var = q2 * (1.f / 1024.f) - mu * mu;
  const float rs = rsqrtf(var + 1e-5f);
  float4 gv = *(const float4*)(g + e);
  float4 be = *(const float4*)(beta + e);
  float o0 = (v0 - mu) * rs * gv.x + be.x;
  float o1 = (v1 - mu) * rs * gv.y + be.y;
  float o2 = (v2 - mu) * rs * gv.z + be.z;
  float o3 = (v3 - mu) * rs * gv.w + be.w;
  ushort4 ob; ob.x = f2bf(o0); ob.y = f2bf(o1); ob.z = f2bf(o2); ob.w = f2bf(o3);
  *(ushort4*)(yb + base) = ob;
}

// x = src + pe(batch, e), vectorized x4 (1048576 float4 units -> 4096 blocks)
__global__ __launch_bounds__(256) void pe_add_k(const float* __restrict__ src,
    u16* __restrict__ xb)
{
  const int u = blockIdx.x * 256 + threadIdx.x;
  const int e4 = (u & 255) * 4;
  const int b = u >> 17;
  const float C = -18.420680743952367f * (1.f / 1024.f);
  float4 sv = ((const float4*)src)[u];
  float fb = (float)b;
  float fr0 = __expf((float)(e4 >> 1) * C);
  float fr1 = __expf((float)((e4 >> 1) + 1) * C);
  float a0 = fb * fr0, a1 = fb * fr1;
  ushort4 ov;
  ov.x = f2bf(sv.x + __sinf(a0));
  ov.y = f2bf(sv.y + __cosf(a0));
  ov.z = f2bf(sv.z + __sinf(a1));
  ov.w = f2bf(sv.w + __cosf(a1));
  ((ushort4*)xb)[u] = ov;
}

__global__ __launch_bounds__(256) void cvt4_k(const float* __restrict__ s0,
    const float* __restrict__ s1, const float* __restrict__ s2,
    const float* __restrict__ s3, u16* __restrict__ dst)
{
  int i = blockIdx.x * 256 + threadIdx.x;
  const float* s; size_t off;
  if (i < 786432)       { s = s0; off = (size_t)i; }
  else if (i < 1048576) { s = s1; off = (size_t)i - 786432; }
  else if (i < 2097152) { s = s2; off = (size_t)i - 1048576; }
  else                  { s = s3; off = (size_t)i - 2097152; }
  float4 v = ((const float4*)s)[off];
  ushort4 ov; ov.x = f2bf(v.x); ov.y = f2bf(v.y); ov.z = f2bf(v.z); ov.w = f2bf(v.w);
  ((ushort4*)dst)[i] = ov;
}

__global__ __launch_bounds__(256) void head_k(const u16* __restrict__ xb,
    const float* __restrict__ hw, const float* __restrict__ hb, float* __restrict__ out)
{
  const int b = blockIdx.x, tid = threadIdx.x;
  const ushort4 xv = ((const ushort4*)(xb + ((size_t)b * 512 + 511) * 1024))[tid];
  const float4 wv = ((const float4*)hw)[tid];
  float s = bf2f(xv.x) * wv.x + bf2f(xv.y) * wv.y + bf2f(xv.z) * wv.z + bf2f(xv.w) * wv.w;
  #pragma unroll
  for (int m = 1; m < 64; m <<= 1) s += __shfl_xor(s, m);
  __shared__ float ls[4];
  if ((tid & 63) == 0) ls[tid >> 6] = s;
  __syncthreads();
  if (tid == 0) out[b] = ls[0] + ls[1] + ls[2] + ls[3] + hb[0];
}

// ---------------------------------------------------------------------------
extern "C" void kernel_launch(void* const* d_in, const int* in_sizes, int n_in,
                              void* d_out, int out_size, void* d_ws, size_t ws_size,
                              hipStream_t stream)
{
  const float* src  = (const float*)d_in[0];
  const float* ipw  = (const float*)d_in[1];
  const float* ipb  = (const float*)d_in[2];
  const float* outw = (const float*)d_in[3];
  const float* outb = (const float*)d_in[4];
  const float* f1w  = (const float*)d_in[5];
  const float* f1b  = (const float*)d_in[6];
  const float* f2w  = (const float*)d_in[7];
  const float* f2b  = (const float*)d_in[8];
  const float* l1g  = (const float*)d_in[9];
  const float* l1b  = (const float*)d_in[10];
  const float* l2g  = (const float*)d_in[11];
  const float* l2b  = (const float*)d_in[12];
  const float* hw   = (const float*)d_in[13];
  const float* hb   = (const float*)d_in[14];

  char* p = (char*)d_ws;
  auto take = [&](size_t bytes) { char* r = p; p += (bytes + 255) & ~(size_t)255; return r; };
  u16*   xb   = (u16*)  take(4096ull * 1024 * 2);
  u16*   slA  = (u16*)  take(4096ull * 4096 * 2);
  u16*   ob   = (u16*)  take(4096ull * 1024 * 2);
  u16*   pf   = (u16*)  take(4ull * 4096 * 1024 * 2);
  u16*   wc   = (u16*)  take(12582912ull * 2);

  u16* qkvb = slA;
  u16* f1o  = slA;

  pe_add_k<<<4096, 256, 0, stream>>>(src, xb);

  for (int l = 0; l < 4; ++l) {
    cvt4_k<<<12288, 256, 0, stream>>>(ipw + (size_t)l * 3145728,
                                      outw + (size_t)l * 1048576,
                                      f1w + (size_t)l * 4194304,
                                      f2w + (size_t)l * 4194304, wc);
    // QKV: [4096,3072], K=1024
    gemm9<0><<<192, 512, 0, stream>>>(xb, wc, ipb + l * 3072, qkvb, 3072, 1024, 1024, 12, 16);
    attn_f<<<1024, 256, 0, stream>>>(qkvb, ob);
    // out-proj: N=1024, K=1024, split-K=4
    gemm9<2><<<256, 512, 0, stream>>>(ob, wc + 3145728, nullptr, pf, 1024, 1024, 256, 4, 16);
    ln_res4_k<<<4096, 256, 0, stream>>>(xb, pf, outb + l * 1024, l1g + l * 1024, l1b + l * 1024, xb);
    // FF1: [4096,4096], K=1024, ReLU
    gemm9<1><<<256, 512, 0, stream>>>(xb, wc + 4194304, f1b + l * 4096, f1o, 4096, 1024, 1024, 16, 16);
    // FF2: N=1024, K=4096, split-K=4
    gemm9<2><<<256, 512, 0, stream>>>(f1o, wc + 8388608, nullptr, pf, 1024, 4096, 1024, 4, 16);
    ln_res4_k<<<4096, 256, 0, stream>>>(xb, pf, f2b + l * 1024, l2g + l * 1024, l2b + l * 1024, xb);
  }
  head_k<<<8, 256, 0, stream>>>(xb, hw, hb, (float*)d_out);
}